// Round 3
// baseline (295.682 us; speedup 1.0000x reference)
//
#include <hip/hip_runtime.h>

// QuantumRecurrentUnit, exact Heisenberg closed form.
//   rev_q = (p_q + x_q)/2pi ;  sa=sin, ca=cos of the angle
//   p_q' = cos(th_q)*prefixprod_{j<=q} ca_j - sin(th_q)*(q<5 ? sa_q*sa_{q+1} : sa_5)
//
// v4: S=4 high-concurrency all-global design.
//  - 256 windows/chain (S=4), 256-thread blocks, 8192 waves total -> up to
//    8 waves/SIMD vs v3's ~2 resident streams. The kernel is latency-bound
//    (VALUBusy 14%, occupancy 27%): streams are the lever, issue work (1.8x)
//    is cheap.
//  - explicit __launch_bounds__(256, 4): 128-VGPR budget. v3's bare
//    launch_bounds let the allocator crush to 32 VGPRs and churn the ~70-float
//    live set through remat/AGPR moves (~2.5x instruction inflation measured
//    via VALUBusy*dur). v2's (128,4) + 48-reg array spilled to scratch
//    (253 MB phantom WRITE_SIZE). 128 regs for an ~80-reg live set is the
//    sane middle.
//  - at S=4 a wave sweeps a compact ~290-row (18 KB) window in near-lockstep,
//    so row re-reads (<=10 lanes/row) stay L1/L2-resident -> FETCH back
//    toward compulsory ~64 MB (v3: 174 MB from temporally-scattered re-reads).
//  - burn-in W=32 and exact t=0 reset unchanged (same verified numerics);
//    reset boundaries generalized to S=4: lanes 0..7 restart exactly when
//    their window crosses t=0.

constexpr int T = 1024;
constexpr int NQ = 6;
constexpr int S = 4;         // output steps per lane
constexpr int W = 32;        // burn-in steps
constexpr int TOT = W + S;   // 36
constexpr int PF = 4;        // prefetch depth (TOT % PF == 0)
constexpr float INV2PI = 0.15915494309189535f;  // v_sin/v_cos take revolutions

__global__ __launch_bounds__(256, 4) void qru_kernel(const float* __restrict__ x,
                                                     const float* __restrict__ w,
                                                     float* __restrict__ out) {
  const int L = threadIdx.x;   // window index within chain, 0..255
  const int chain = blockIdx.x;
  const float* __restrict__ xb = x + (size_t)chain * (T * 16);
  float* __restrict__ ob = out + (size_t)chain * (T * NQ);
  const int tbase = L * S - W;  // lanes 0..7: window crosses t=0

  float cth[NQ], sth[NQ];
#pragma unroll
  for (int q = 0; q < NQ; ++q) {
    const float th = w[q];
    cth[q] = cosf(th);
    sth[q] = sinf(th);
  }

  float p[NQ];
#pragma unroll
  for (int q = 0; q < NQ; ++q) p[q] = 0.0f;

  // Pipeline buffers: raw (unscaled) angles for steps I..I+3.
  float b0[NQ], b1[NQ], b2[NQ], b3[NQ];

  // Load the 6 raw angles of step I's row into B (float4+float2, 16B-aligned;
  // touches only the first 32B sector of the 64B row).
#define LOADROW(I, B)                                                          \
  do {                                                                         \
    int r_ = tbase + (I);                                                      \
    r_ = r_ < 0 ? 0 : r_; /* burn-in underrun: dummy row 0, exact reset follows */ \
    const float* rp_ = xb + (size_t)r_ * 16;                                   \
    const float4 v4_ = *(const float4*)rp_;                                    \
    const float2 v2_ = *(const float2*)(rp_ + 4);                              \
    B[0] = v4_.x;                                                              \
    B[1] = v4_.y;                                                              \
    B[2] = v4_.z;                                                              \
    B[3] = v4_.w;                                                              \
    B[4] = v2_.x;                                                              \
    B[5] = v2_.y;                                                              \
  } while (0)

  // One recurrence step consuming B; refills B with step I+PF right after the
  // buffer is freed (rev computed), so the load leads its use by PF steps.
#define STEP(I, B)                                                             \
  do {                                                                         \
    if ((I) >= S && (I) <= W && ((I) % S) == 0) {                              \
      const bool rs_ = (tbase + (I) == 0); /* window crosses t=0: exact restart */ \
      _Pragma("unroll") for (int q_ = 0; q_ < NQ; ++q_)                        \
          p[q_] = rs_ ? 0.0f : p[q_];                                          \
    }                                                                          \
    float rev_[NQ];                                                            \
    _Pragma("unroll") for (int q_ = 0; q_ < NQ; ++q_)                          \
        rev_[q_] = (p[q_] + B[q_]) * INV2PI;                                   \
    if ((I) + PF < TOT) LOADROW((I) + PF, B); /* buffer free: issue refill */  \
    float sa_[NQ], ca_[NQ];                                                    \
    _Pragma("unroll") for (int q_ = 0; q_ < NQ; ++q_) {                        \
      sa_[q_] = __builtin_amdgcn_sinf(rev_[q_]);                               \
      ca_[q_] = __builtin_amdgcn_cosf(rev_[q_]);                               \
    }                                                                          \
    const float t01_ = ca_[0] * ca_[1];                                        \
    const float t23_ = ca_[2] * ca_[3];                                        \
    const float t45_ = ca_[4] * ca_[5];                                        \
    const float P2_ = t01_ * ca_[2];                                           \
    const float P3_ = t01_ * t23_;                                             \
    const float P4_ = P3_ * ca_[4];                                            \
    const float P5_ = P3_ * t45_;                                              \
    p[0] = cth[0] * ca_[0] - sth[0] * (sa_[0] * sa_[1]);                       \
    p[1] = cth[1] * t01_ - sth[1] * (sa_[1] * sa_[2]);                         \
    p[2] = cth[2] * P2_ - sth[2] * (sa_[2] * sa_[3]);                          \
    p[3] = cth[3] * P3_ - sth[3] * (sa_[3] * sa_[4]);                          \
    p[4] = cth[4] * P4_ - sth[4] * (sa_[4] * sa_[5]);                          \
    p[5] = cth[5] * P5_ - sth[5] * sa_[5];                                     \
    if ((I) >= W) { /* uniform branch: I is compile-time */                    \
      float2* op_ = (float2*)(ob + (size_t)(tbase + (I)) * NQ);                \
      op_[0] = make_float2(p[0], p[1]);                                        \
      op_[1] = make_float2(p[2], p[3]);                                        \
      op_[2] = make_float2(p[4], p[5]);                                        \
    }                                                                          \
  } while (0)

  LOADROW(0, b0);
  LOADROW(1, b1);
  LOADROW(2, b2);
  LOADROW(3, b3);

#pragma unroll
  for (int i = 0; i < TOT; i += PF) {  // 9 iterations, fully unrolled
    STEP(i + 0, b0);
    STEP(i + 1, b1);
    STEP(i + 2, b2);
    STEP(i + 3, b3);
  }
#undef LOADROW
#undef STEP
}

extern "C" void kernel_launch(void* const* d_in, const int* in_sizes, int n_in,
                              void* d_out, int out_size, void* d_ws, size_t ws_size,
                              hipStream_t stream) {
  const float* x = (const float*)d_in[0];
  const float* w = (const float*)d_in[1];
  float* out = (float*)d_out;
  const int B = in_sizes[0] / (T * 16);  // 2048 chains
  qru_kernel<<<B, 256, 0, stream>>>(x, w, out);
}

// Round 4
// 224.020 us; speedup vs baseline: 1.3199x; 1.3199x over previous
//
#include <hip/hip_runtime.h>

// QuantumRecurrentUnit, exact Heisenberg closed form + time-chunking + LDS staging.
//   rev_q = (p_q + x_q)/2pi ;  sa=sin, ca=cos of the angle
//   p_q' = cos(th_q)*prefixprod_{j<=q} ca_j - sin(th_q)*(q<5 ? sa_q*sa_{q+1} : sa_5)
//
// v5 = v1 (verified 110 us dispatch) + two targeted fixes for the measured
// per-step serial costs; geometry/staging/swizzle/numerics IDENTICAL to v1.
//  (a) distance-4 register prefetch of per-step LDS angles: v1 issued its 6
//      ds_read_b32 at use (68 VGPRs left no hoist room), exposing ~120 cy of
//      LDS latency on every step's dependent chain. 4 rotating 6-float buffers,
//      refilled right after each buffer's rev is computed, put ~3.5 steps of
//      compute under the read latency.
//  (b) pairwise-buffered float4 stores: buffer one output row (6 regs), then
//      3x float4 per 2 rows (48 B contiguous/lane, 16B-aligned since the pair
//      starts at row 8l+even). Halves scattered-store instruction count
//      (24 -> 12 per lane) -> halves VMEM address-path cost, and full 64-B
//      lines per lane let L2 write-combine (v1: 80 MB WRITE for 50 MB useful).
// v3/v4 lesson kept: all-global per-step fetch is a 64-line/instr scatter that
// saturates the CU memory front-end -- LDS staging stays.

constexpr int T = 1024;
constexpr int NQ = 6;
constexpr int S = 8;         // output steps per lane
constexpr int W = 32;        // burn-in steps
constexpr int TOT = W + S;   // 40
constexpr int PF = 4;        // LDS->reg prefetch distance (TOT % PF == 0)
constexpr float INV2PI = 0.15915494309189535f;  // v_sin/v_cos take revolutions

// Swizzled LDS index for (row r, component q). Compute phase: r = 8l + c
// -> addr = 48l + 6c + l + const == 17*l + const (mod 32); 17 odd => lanes
// l and l+32 share a bank (2-way = free), all else distinct.
__device__ __forceinline__ int lidx(int r, int q) { return r * 6 + q + (r >> 3); }

constexpr int LDS_FLOATS = (T - 1) * 6 + 5 + ((T - 1) >> 3) + 1;  // 6271 -> 25.1 KiB

__global__ __launch_bounds__(128, 3) void qru_kernel(const float* __restrict__ x,
                                                     const float* __restrict__ w,
                                                     float* __restrict__ out) {
  __shared__ float lx[LDS_FLOATS];
  const int l = threadIdx.x;   // 0..127
  const int chain = blockIdx.x;
  const float* __restrict__ xb = x + (size_t)chain * (T * 16);
  float* __restrict__ ob = out + (size_t)chain * (T * NQ);

  // ---- phase 1: stage x[chain][:, 0:6]*INV2PI into swizzled LDS ----
  // (verbatim v1) 16 VMEM instrs per lane, all in flight before any LDS write.
  float4 va[8];
  float2 vb[8];
#pragma unroll
  for (int j = 0; j < 8; ++j) {
    const int r = j * 128 + l;
    va[j] = *(const float4*)(xb + (size_t)r * 16);
    vb[j] = *(const float2*)(xb + (size_t)r * 16 + 4);
  }
  __builtin_amdgcn_sched_barrier(0);  // keep loads batched ahead of LDS writes
#pragma unroll
  for (int j = 0; j < 8; ++j) {
    const int r = j * 128 + l;
    const int base = lidx(r, 0);
    lx[base + 0] = va[j].x * INV2PI;
    lx[base + 1] = va[j].y * INV2PI;
    lx[base + 2] = va[j].z * INV2PI;
    lx[base + 3] = va[j].w * INV2PI;
    lx[base + 4] = vb[j].x * INV2PI;
    lx[base + 5] = vb[j].y * INV2PI;
  }
  __syncthreads();

  // ---- phase 2: per-lane chunk recurrence from LDS, prefetched PF deep ----
  float cth[NQ], sth[NQ];
#pragma unroll
  for (int q = 0; q < NQ; ++q) {
    const float th = w[q];
    cth[q] = cosf(th);
    sth[q] = sinf(th);
  }

  float p[NQ];
#pragma unroll
  for (int q = 0; q < NQ; ++q) p[q] = 0.0f;

  const int tbase = l * S - W;  // lanes 0..3: negative (window crosses t=0)

  float b0[NQ], b1[NQ], b2[NQ], b3[NQ];  // prescaled angles, steps I..I+3
  float sv[NQ];                          // buffered even output row

  // Read the 6 prescaled angles of step I's row from LDS into B.
#define FETCHL(I, B)                                                           \
  do {                                                                         \
    int r_ = tbase + (I);                                                      \
    r_ = r_ < 0 ? 0 : r_; /* burn-in underrun: dummy row 0, exact reset follows */ \
    const int base_ = lidx(r_, 0);                                             \
    _Pragma("unroll") for (int q_ = 0; q_ < NQ; ++q_) B[q_] = lx[base_ + q_];  \
  } while (0)

  // One recurrence step consuming B; refills B with step I+PF right after the
  // buffer is freed (rev computed), so the ds_reads lead their use by ~3.5
  // steps of trans/VALU work.
#define STEP(I, B)                                                             \
  do {                                                                         \
    if ((I) >= 8 && (I) <= 32 && ((I)&7) == 0) {                               \
      const bool rs_ = (tbase + (I) == 0); /* window crosses t=0: exact restart */ \
      _Pragma("unroll") for (int q_ = 0; q_ < NQ; ++q_)                        \
          p[q_] = rs_ ? 0.0f : p[q_];                                          \
    }                                                                          \
    float rev_[NQ];                                                            \
    _Pragma("unroll") for (int q_ = 0; q_ < NQ; ++q_)                          \
        rev_[q_] = fmaf(p[q_], INV2PI, B[q_]); /* x pre-scaled by 1/2pi */     \
    if ((I) + PF < TOT) FETCHL((I) + PF, B);   /* buffer free: issue refill */ \
    float sa_[NQ], ca_[NQ];                                                    \
    _Pragma("unroll") for (int q_ = 0; q_ < NQ; ++q_) {                        \
      sa_[q_] = __builtin_amdgcn_sinf(rev_[q_]);                               \
      ca_[q_] = __builtin_amdgcn_cosf(rev_[q_]);                               \
    }                                                                          \
    const float t01_ = ca_[0] * ca_[1];                                        \
    const float t23_ = ca_[2] * ca_[3];                                        \
    const float t45_ = ca_[4] * ca_[5];                                        \
    const float P2_ = t01_ * ca_[2];                                           \
    const float P3_ = t01_ * t23_;                                             \
    const float P4_ = P3_ * ca_[4];                                            \
    const float P5_ = P3_ * t45_;                                              \
    p[0] = cth[0] * ca_[0] - sth[0] * (sa_[0] * sa_[1]);                       \
    p[1] = cth[1] * t01_ - sth[1] * (sa_[1] * sa_[2]);                         \
    p[2] = cth[2] * P2_ - sth[2] * (sa_[2] * sa_[3]);                          \
    p[3] = cth[3] * P3_ - sth[3] * (sa_[3] * sa_[4]);                          \
    p[4] = cth[4] * P4_ - sth[4] * (sa_[4] * sa_[5]);                          \
    p[5] = cth[5] * P5_ - sth[5] * sa_[5];                                     \
    if ((I) >= W) { /* uniform branch: I is compile-time */                    \
      if ((((I)-W) & 1) == 0) { /* even output step: buffer the row */         \
        _Pragma("unroll") for (int q_ = 0; q_ < NQ; ++q_) sv[q_] = p[q_];      \
      } else { /* odd step: emit rows I-1,I as 3x float4 (48 B contiguous) */  \
        float* bp_ = ob + (size_t)(tbase + (I)-1) * NQ;                        \
        *(float4*)(bp_ + 0) = make_float4(sv[0], sv[1], sv[2], sv[3]);         \
        *(float4*)(bp_ + 4) = make_float4(sv[4], sv[5], p[0], p[1]);           \
        *(float4*)(bp_ + 8) = make_float4(p[2], p[3], p[4], p[5]);             \
      }                                                                        \
    }                                                                          \
  } while (0)

  FETCHL(0, b0);
  FETCHL(1, b1);
  FETCHL(2, b2);
  FETCHL(3, b3);

#pragma unroll
  for (int i = 0; i < TOT; i += PF) {  // 10 iterations, fully unrolled
    STEP(i + 0, b0);
    STEP(i + 1, b1);
    STEP(i + 2, b2);
    STEP(i + 3, b3);
  }
#undef FETCHL
#undef STEP
}

extern "C" void kernel_launch(void* const* d_in, const int* in_sizes, int n_in,
                              void* d_out, int out_size, void* d_ws, size_t ws_size,
                              hipStream_t stream) {
  const float* x = (const float*)d_in[0];
  const float* w = (const float*)d_in[1];
  float* out = (float*)d_out;
  const int B = in_sizes[0] / (T * 16);  // 2048 chains
  qru_kernel<<<B, 128, 0, stream>>>(x, w, out);
}